// Round 5
// baseline (1028.404 us; speedup 1.0000x reference)
//
#include <hip/hip_runtime.h>
#include <hip/hip_bf16.h>
#include <math.h>

// Problem constants (fixed shapes from reference setup_inputs)
#define NS   32      // batch
#define TS   1024    // time steps
#define KIN  2048    // INPUT_SIZE
#define RED  128     // REDUCED
#define HID  32      // HIDDEN
#define G3   96      // 3*HIDDEN
#define SEQ  8       // x.shape[1] — x data itself is never used

#define GX_FLOATS (NS * TS * G3)   // 3,145,728
#define W_ELEMS   (G3 * KIN)       // 196,608 bf16 elements per buffer

#define SCAN_BLOCKS 8              // 4 waves each -> 32 samples
#define GEMM_BLOCKS 128            // 32 n x 4 row-strips (32 rows each)
#define STRIPS_PER_TILE 4          // 128-row tile / 32-row strip

typedef __attribute__((ext_vector_type(8))) short  short8;   // 8 bf16 (4 VGPRs)
typedef __attribute__((ext_vector_type(4))) float  floatx4;  // MFMA accumulator
typedef __attribute__((ext_vector_type(2))) float  floatx2;
typedef __attribute__((ext_vector_type(2))) unsigned int uint2v;

// fea_len may arrive as int32 or int64. int64 little-endian with values
// < 2^31 => odd int32 words are all zero.
__device__ __forceinline__ int load_len(const int* __restrict__ p, int n) {
    bool is64 = (p[1] == 0) && (p[3] == 0) && (p[5] == 0) && (p[7] == 0);
    if (is64) return (int)((const long long*)p)[n];
    return p[n];
}

// scalar fp32 -> bf16 (RNE) and back (exact)
__device__ __forceinline__ unsigned short f2bf(float x) {
    unsigned u = __float_as_uint(x);
    unsigned r = u + 0x7fffu + ((u >> 16) & 1u);
    return (unsigned short)(r >> 16);
}
__device__ __forceinline__ float bfu2f(unsigned short u) {
    return __uint_as_float(((unsigned)u) << 16);
}

// v_exp_f32 computes 2^x; expose it directly (weights are pre-scaled by log2e)
__device__ __forceinline__ float fexp2(float x) {
#if __has_builtin(__builtin_amdgcn_exp2f)
    return __builtin_amdgcn_exp2f(x);
#else
    return exp2f(x);
#endif
}

// ---- permlane swaps: builtin if available, raw instruction otherwise ------
__device__ __forceinline__ void swap16(unsigned& a, unsigned& b) {
#if __has_builtin(__builtin_amdgcn_permlane16_swap)
    uint2v r = __builtin_amdgcn_permlane16_swap(a, b, false, false);
    a = r.x; b = r.y;
#else
    asm("v_permlane16_swap_b32 %0, %1" : "+v"(a), "+v"(b));
#endif
}
__device__ __forceinline__ void swap32(unsigned& a, unsigned& b) {
#if __has_builtin(__builtin_amdgcn_permlane32_swap)
    uint2v r = __builtin_amdgcn_permlane32_swap(a, b, false, false);
    a = r.x; b = r.y;
#else
    asm("v_permlane32_swap_b32 %0, %1" : "+v"(a), "+v"(b));
#endif
}

// sum over lane pairs (l, l^32): direction-independent (a+b covers both)
__device__ __forceinline__ float xor32sum(float x) {
    unsigned a = __float_as_uint(x), b = a;
    swap32(a, b);
    return __uint_as_float(a) + __uint_as_float(b);
}

#define DPPM(srcv, ctrl) __uint_as_float((unsigned)__builtin_amdgcn_update_dpp( \
        (int)__float_as_uint(srcv), (int)__float_as_uint(srcv), (ctrl), 0xF, 0xF, false))

// coherence-point load (bypasses stale per-XCD cache state; latency hidden
// by the scan's 8-step prefetch ring)
__device__ __forceinline__ float aload(const float* p) {
    return __uint_as_float(__hip_atomic_load((const unsigned*)p,
            __ATOMIC_RELAXED, __HIP_MEMORY_SCOPE_AGENT));
}
// spin until tile counter reaches STRIPS_PER_TILE (producer release-adds)
__device__ __forceinline__ void wait_tile(const unsigned* c) {
    while (__hip_atomic_load(c, __ATOMIC_ACQUIRE, __HIP_MEMORY_SCOPE_AGENT)
           < (unsigned)STRIPS_PER_TILE) {
        __builtin_amdgcn_s_sleep(2);
    }
}

// packed hi/lo split of 8 floats -> two bf16x8 fragments
__device__ __forceinline__ void cvt_hilo(const float* f, short8& hi, short8& lo) {
    #pragma unroll
    for (int p = 0; p < 4; ++p) {
        float2 fv = make_float2(f[2*p], f[2*p+1]);
        union { __hip_bfloat162 b2; unsigned short us[2]; } H, L;
        H.b2 = __float22bfloat162_rn(fv);
        float2 hb = __bfloat1622float2(H.b2);
        L.b2 = __float22bfloat162_rn(make_float2(fv.x - hb.x, fv.y - hb.y));
        hi[2*p] = (short)H.us[0]; hi[2*p+1] = (short)H.us[1];
        lo[2*p] = (short)L.us[0]; lo[2*p+1] = (short)L.us[1];
    }
}

// ---------------------------------------------------------------------------
// K1: W_comb = W_ih @ W_ann (96 x 2048), emitted as bf16 hi/lo pair;
//     b_comb[j] = b_ih[j] + W_ih[j]·b_ann.  Block 768 also zeroes the
//     per-(n,tile) completion counters used by the fused kernel.
// ---------------------------------------------------------------------------
__global__ __launch_bounds__(256) void k_prep(
        const float* __restrict__ W_ann, const float* __restrict__ b_ann,
        const float* __restrict__ W_ih,  const float* __restrict__ b_ih,
        unsigned short* __restrict__ Whi, unsigned short* __restrict__ Wlo,
        float* __restrict__ b_comb, unsigned* __restrict__ cnt) {
    if (blockIdx.x == 768) {
        int j = threadIdx.x;
        cnt[j] = 0;                     // 256 = NS*8 tile counters
        if (j < G3) {
            float acc = b_ih[j];
            #pragma unroll 8
            for (int m = 0; m < RED; ++m) acc += W_ih[j * RED + m] * b_ann[m];
            b_comb[j] = acc;
        }
        return;
    }
    int id = blockIdx.x * 256 + threadIdx.x;   // 0 .. 196607
    int j = id >> 11;          // /2048
    int k = id & (KIN - 1);
    float acc = 0.0f;
    #pragma unroll 8
    for (int m = 0; m < RED; ++m) acc += W_ih[j * RED + m] * W_ann[m * KIN + k];
    unsigned short h = f2bf(acc);
    Whi[id] = h;
    Wlo[id] = f2bf(acc - bfu2f(h));
}

// ---------------------------------------------------------------------------
// Fused K2+K3. Producer-consumer overlap inside one kernel:
//   blocks 0..7           : scan role (4 waves, 1 sample each)
//   blocks 8..8+127       : gemm role; block (n = b&31, q = b>>5) computes the
//                           32-row strip q of EVERY tile ty = 0..7 in ascending
//                           order, so tile availability ramps ~T_gemm/8 per
//                           tile while the scan consumes ~26 us per tile.
// Sync: per-(n,ty) counter. Producer: stores -> __threadfence (agent release,
// L2 writeback) -> __syncthreads -> release atomic add. Consumer: acquire
// spin; gx ring loads are relaxed agent atomics (coherence-point reads).
// All 136 blocks are co-resident (<= 1 block/CU) and producers never wait,
// so the spin cannot deadlock. Math is bit-identical to the split kernels.
// ---------------------------------------------------------------------------
__device__ __forceinline__ void gemm_role(
        const float* __restrict__ fea, const int* __restrict__ flen,
        const unsigned short* __restrict__ Whi,
        const unsigned short* __restrict__ Wlo,
        const float* __restrict__ b_comb,
        float* __restrict__ gx, unsigned* __restrict__ cnt) {
    const int b2 = blockIdx.x - SCAN_BLOCKS;
    const int n  = b2 & 31;
    const int q  = b2 >> 5;                 // 0..3 : 32-row strip within tile
    const int L  = load_len(flen, n) + SEQ;

    const int tid  = threadIdx.x;
    const int w    = tid >> 6;              // wave 0..3
    const int ln   = tid & 63;
    const int mr   = ln & 15;
    const int quad = ln >> 4;
    const int mf   = w & 1;                 // 16-row half of the strip
    const int nfb  = (w >> 1) * 3;          // col-frag base: 0 or 3

    int boff[3];
    #pragma unroll
    for (int nf2 = 0; nf2 < 3; ++nf2)
        boff[nf2] = ((nfb + nf2) * 16 + mr) * KIN + quad * 8;

    for (int ty = 0; ty < 8; ++ty) {
        const int t0 = ty * 128 + q * 32;
        if (t0 < L) {   // block-uniform
            const size_t arow =
                ((size_t)(n * TS + t0 + mf * 16 + mr)) * KIN + quad * 8;
            floatx4 acc[3];
            #pragma unroll
            for (int nf2 = 0; nf2 < 3; ++nf2) acc[nf2] = (floatx4){0.f,0.f,0.f,0.f};

            #pragma unroll 1
            for (int c = 0; c < KIN / 64; ++c) {
                #pragma unroll
                for (int ks = 0; ks < 2; ++ks) {
                    const int ko = c * 64 + ks * 32;
                    float fa[8];
                    {
                        float4 a0 = *(const float4*)(fea + arow + ko);
                        float4 a1 = *(const float4*)(fea + arow + ko + 4);
                        fa[0]=a0.x; fa[1]=a0.y; fa[2]=a0.z; fa[3]=a0.w;
                        fa[4]=a1.x; fa[5]=a1.y; fa[6]=a1.z; fa[7]=a1.w;
                    }
                    short8 ah, al;
                    cvt_hilo(fa, ah, al);
                    #pragma unroll
                    for (int nf2 = 0; nf2 < 3; ++nf2) {
                        short8 bh = *(const short8*)(Whi + boff[nf2] + ko);
                        short8 bl = *(const short8*)(Wlo + boff[nf2] + ko);
                        acc[nf2] = __builtin_amdgcn_mfma_f32_16x16x32_bf16(ah, bh, acc[nf2], 0, 0, 0);
                        acc[nf2] = __builtin_amdgcn_mfma_f32_16x16x32_bf16(ah, bl, acc[nf2], 0, 0, 0);
                        acc[nf2] = __builtin_amdgcn_mfma_f32_16x16x32_bf16(al, bh, acc[nf2], 0, 0, 0);
                    }
                }
            }
            // epilogue: D row=(lane>>4)*4+r, col=lane&15
            const int tbase = t0 + mf * 16 + quad * 4;
            #pragma unroll
            for (int nf2 = 0; nf2 < 3; ++nf2) {
                const float bc = b_comb[(nfb + nf2) * 16 + mr];
                float* gp = gx + ((size_t)(n * TS + tbase)) * G3 + (nfb + nf2) * 16 + mr;
                #pragma unroll
                for (int r = 0; r < 4; ++r)
                    gp[(size_t)r * G3] = acc[nf2][r] + bc;
            }
        }
        // publish strip completion (always, even when compute skipped)
        __threadfence();        // agent-scope release: drain + L2 writeback
        __syncthreads();        // all 4 waves' fences done
        if (tid == 0)
            __hip_atomic_fetch_add(&cnt[n * 8 + ty], 1u,
                                   __ATOMIC_RELEASE, __HIP_MEMORY_SCOPE_AGENT);
    }
}

__device__ __forceinline__ void scan_role(
        const float* __restrict__ gx, const int* __restrict__ flen,
        const float* __restrict__ W_hh, const float* __restrict__ b_hh,
        const float* __restrict__ W_q,  const float* __restrict__ b_q,
        float* __restrict__ out, const unsigned* __restrict__ cnt) {
    const int tid  = threadIdx.x;
    const int wv   = tid >> 6;
    const int lane = tid & 63;
    const int n    = blockIdx.x * 4 + wv;
    const int j    = lane & 31;   // hidden unit / gate row
    const int kh   = lane >> 5;   // K-half
    const int l15  = lane & 15;
    const int L    = load_len(flen, n) + SEQ;   // L >= 8 always

    const float LOG2E = 1.4426950408889634f;

    // butterfly xor-mask order: hv reg m holds h[kh*16 + (l15 ^ MT[m])]
    const int MT[16] = {0,1,2,3, 7,6,5,4, 15,14,13,12, 8,9,10,11};

    // per-lane recurrent weights, permuted to match the butterfly layout and
    // PRE-SCALED: r,z by -log2e (sigmoid via 2^s), n by +2log2e (tanh via 2^s)
    floatx2 wr2[8], wz2[8], wn2[8];
    #pragma unroll
    for (int k2 = 0; k2 < 8; ++k2) {
        const int ka = kh * 16 + (l15 ^ MT[2*k2]);
        const int kb = kh * 16 + (l15 ^ MT[2*k2+1]);
        wr2[k2].x = -LOG2E * W_hh[(size_t)(j)      * HID + ka];
        wr2[k2].y = -LOG2E * W_hh[(size_t)(j)      * HID + kb];
        wz2[k2].x = -LOG2E * W_hh[(size_t)(32 + j) * HID + ka];
        wz2[k2].y = -LOG2E * W_hh[(size_t)(32 + j) * HID + kb];
        wn2[k2].x = 2.0f * LOG2E * W_hh[(size_t)(64 + j) * HID + ka];
        wn2[k2].y = 2.0f * LOG2E * W_hh[(size_t)(64 + j) * HID + kb];
    }
    const float mh  = -0.5f * LOG2E;
    const float brm = mh * b_hh[j];
    const float bzm = mh * b_hh[32 + j];
    const float bnm = LOG2E * b_hh[64 + j];
    const float xnf = 2.0f * LOG2E;
    const float wq  = W_q[j];
    const float bq  = b_q[0];
    const bool  hi  = (lane >= 32);

    // one-time probe: resolve permlane16_swap direction into one cndmask cond
    bool selY;
    {
        unsigned a = (unsigned)lane, b = (unsigned)lane;
        swap16(a, b);
        const bool dirA = ((a & 16u) == 0u);
        selY = dirA ? hi : !hi;
    }

    const float* gbase = gx + (size_t)n * TS * G3;
    const unsigned* cn = cnt + n * 8;
    const int tclip = (L - 1) >> 7;          // last tile ever consumed

    // tile 0 must be complete before the initial ring load
    wait_tile(cn + 0);
    int twait = 0;

    // depth-8 register prefetch ring; both halves load identical addresses.
    float rg[8][3];
    #pragma unroll
    for (int i = 0; i < 8; ++i) {
        const float* p = gbase + (size_t)i * G3;
        rg[i][0] = aload(p + j); rg[i][1] = aload(p + 32 + j); rg[i][2] = aload(p + 64 + j);
    }

    floatx2 hv2[8];
    #pragma unroll
    for (int k2 = 0; k2 < 8; ++k2) hv2[k2] = (floatx2){0.f, 0.f};
    float h = 0.0f, qacc = 0.0f;

    #define GRU_STEP(XR, XZ, XN, DO_UPDATE)                                   \
    {                                                                         \
        floatx2 aA = (floatx2){__builtin_fmaf(mh, (XR), brm), 0.f};           \
        floatx2 zA = (floatx2){__builtin_fmaf(mh, (XZ), bzm), 0.f};           \
        floatx2 nA = (floatx2){bnm, 0.f};                                     \
        floatx2 aB = (floatx2){0.f, 0.f}, zB = aB, nB = aB;                   \
        const float xn2 = xnf * (XN);                                         \
        _Pragma("unroll")                                                     \
        for (int k2 = 0; k2 < 4; ++k2) {                                      \
            aA += wr2[k2] * hv2[k2];   aB += wr2[k2+4] * hv2[k2+4];           \
            zA += wz2[k2] * hv2[k2];   zB += wz2[k2+4] * hv2[k2+4];           \
            nA += wn2[k2] * hv2[k2];   nB += wn2[k2+4] * hv2[k2+4];           \
        }                                                                     \
        floatx2 av = aA + aB, zv = zA + zB, nv = nA + nB;                     \
        float sr   = xor32sum(av.x + av.y);                                   \
        float sz   = xor32sum(zv.x + zv.y);                                   \
        float dnb2 = xor32sum(nv.x + nv.y);                                   \
        float r    = __builtin_amdgcn_rcpf(1.0f + fexp2(sr));                 \
        float z    = __builtin_amdgcn_rcpf(1.0f + fexp2(sz));                 \
        float sn   = __builtin_fmaf(r, dnb2, xn2);                            \
        float u    = __builtin_amdgcn_rcpf(1.0f + fexp2(sn));                 \
        float nng  = __builtin_fmaf(-2.0f, u, 1.0f);                          \
        float hnew = __builtin_fmaf(z, h - nng, nng);                         \
        if (DO_UPDATE) {                                                      \
            h = hnew;                                                         \
            qacc = __builtin_fmaf(wq, hnew, qacc);                            \
        }                                                                     \
        {   /* redistribute h -> hv2 (permlane16_swap + DPP butterfly) */     \
            unsigned pa = __float_as_uint(h), pb = pa;                        \
            swap16(pa, pb);                                                   \
            hv2[0].x = selY ? __uint_as_float(pb) : __uint_as_float(pa);      \
            hv2[0].y = DPPM(hv2[0].x, 0xB1);     /* xor1  */                  \
            hv2[1].x = DPPM(hv2[0].x, 0x4E);     /* xor2  */                  \
            hv2[1].y = DPPM(hv2[0].y, 0x4E);     /* xor3  */                  \
            hv2[2].x = DPPM(hv2[0].x, 0x141);    /* xor7  */                  \
            hv2[2].y = DPPM(hv2[0].y, 0x141);    /* xor6  */                  \
            hv2[3].x = DPPM(hv2[1].x, 0x141);    /* xor5  */                  \
            hv2[3].y = DPPM(hv2[1].y, 0x141);    /* xor4  */                  \
            hv2[4].x = DPPM(hv2[0].x, 0x140);    /* xor15 */                  \
            hv2[4].y = DPPM(hv2[0].y, 0x140);    /* xor14 */                  \
            hv2[5].x = DPPM(hv2[1].x, 0x140);    /* xor13 */                  \
            hv2[5].y = DPPM(hv2[1].y, 0x140);    /* xor12 */                  \
            hv2[6].x = DPPM(hv2[2].x, 0x140);    /* xor8  */                  \
            hv2[6].y = DPPM(hv2[2].y, 0x140);    /* xor9  */                  \
            hv2[7].x = DPPM(hv2[3].x, 0x140);    /* xor10 */                  \
            hv2[7].y = DPPM(hv2[3].y, 0x140);    /* xor11 */                  \
        }                                                                     \
    }

    const int Lfull = L & ~7;   // >= 8 since L >= 8

    // predicate-free main loop over full 8-step blocks
    for (int tb = 0; tb < Lfull; tb += 8) {
        // refills this block touch t in [tb+8, tb+15]: ensure their tiles are
        // published (clipped by tclip: loads past L are never consumed)
        int tneed = (tb + 15) >> 7;
        if (tneed > tclip) tneed = tclip;
        while (twait < tneed) { ++twait; wait_tile(cn + twait); }

        #pragma unroll
        for (int i = 0; i < 8; ++i) {
            const int t = tb + i;
            const float xr = rg[i][0], xz = rg[i][1], xn = rg[i][2];
            {   // refill slot i for t+8 (clip; beyond-L garbage never consumed)
                int tl = t + 8; if (tl > TS - 1) tl = TS - 1;
                const float* p = gbase + (size_t)tl * G3;
                rg[i][0] = aload(p + j); rg[i][1] = aload(p + 32 + j); rg[i][2] = aload(p + 64 + j);
            }
            GRU_STEP(xr, xz, xn, true)
        }
    }

    // predicated tail (< 8 steps); ring already holds t = Lfull..Lfull+7
    if (Lfull < L) {
        #pragma unroll
        for (int i = 0; i < 8; ++i) {
            const int t = Lfull + i;
            const float xr = rg[i][0], xz = rg[i][1], xn = rg[i][2];
            GRU_STEP(xr, xz, xn, (t < L))
        }
    }
    #undef GRU_STEP

    // every j counted twice (kh=0 and kh=1 lanes hold identical streams)
    #pragma unroll
    for (int off = 32; off > 0; off >>= 1) qacc += __shfl_xor(qacc, off, 64);
    if (lane == 0) out[n] = qacc * 0.5f / (float)L + bq;
}

__global__ __launch_bounds__(256)
__attribute__((amdgpu_waves_per_eu(1, 2)))
void k_fused(
        const float* __restrict__ fea, const int* __restrict__ flen,
        const unsigned short* __restrict__ Whi,
        const unsigned short* __restrict__ Wlo,
        const float* __restrict__ b_comb, float* __restrict__ gx,
        const float* __restrict__ W_hh, const float* __restrict__ b_hh,
        const float* __restrict__ W_q,  const float* __restrict__ b_q,
        float* __restrict__ out, unsigned* __restrict__ cnt) {
    if (blockIdx.x >= SCAN_BLOCKS) {
        gemm_role(fea, flen, Whi, Wlo, b_comb, gx, cnt);
    } else {
        scan_role(gx, flen, W_hh, b_hh, W_q, b_q, out, cnt);
    }
}

// ---------------------------------------------------------------------------
extern "C" void kernel_launch(void* const* d_in, const int* in_sizes, int n_in,
                              void* d_out, int out_size, void* d_ws, size_t ws_size,
                              hipStream_t stream) {
    // setup_inputs order: x, fea, fea_len, W_ann, b_ann, W_ih, W_hh, b_ih, b_hh, W_q, b_q
    const float* fea   = (const float*)d_in[1];
    const int*   flen  = (const int*)  d_in[2];
    const float* W_ann = (const float*)d_in[3];
    const float* b_ann = (const float*)d_in[4];
    const float* W_ih  = (const float*)d_in[5];
    const float* W_hh  = (const float*)d_in[6];
    const float* b_ih  = (const float*)d_in[7];
    const float* b_hh  = (const float*)d_in[8];
    const float* W_q   = (const float*)d_in[9];
    const float* b_q   = (const float*)d_in[10];
    float* out = (float*)d_out;

    // ws layout: gx fp32 | Whi bf16 | Wlo bf16 | b_comb | cnt (~13.4 MB total)
    float*          ws_f   = (float*)d_ws;
    float*          gx     = ws_f;
    unsigned short* Whi    = (unsigned short*)(ws_f + GX_FLOATS);
    unsigned short* Wlo    = Whi + W_ELEMS;
    float*          b_comb = (float*)(Wlo + W_ELEMS);
    unsigned*       cnt    = (unsigned*)(b_comb + G3);

    k_prep<<<769, 256, 0, stream>>>(W_ann, b_ann, W_ih, b_ih, Whi, Wlo, b_comb, cnt);

    k_fused<<<SCAN_BLOCKS + GEMM_BLOCKS, 256, 0, stream>>>(
        fea, flen, Whi, Wlo, b_comb, gx, W_hh, b_hh, W_q, b_q, out, cnt);
}